// Round 1
// baseline (1024.482 us; speedup 1.0000x reference)
//
#include <hip/hip_runtime.h>
#include <math.h>

#define NN 100000
#define F 64
#define NC 47

// ---------------------------------------------------------------------------
// Edge dtype handling: harness may deliver edge_index as int32 or int64.
// detect_kernel inspects odd 32-bit words (high halves if int64) and writes a
// flag; convert_kernel produces clean int32 src/dst in workspace.
// ---------------------------------------------------------------------------
__global__ void detect_kernel(const void* __restrict__ ei, int* __restrict__ flag) {
    const int* e32 = (const int*)ei;
    int i = threadIdx.x;                 // 64 threads
    int v = e32[2 * i + 1];
    unsigned long long ball = __ballot(v == 0);
    if (i == 0) *flag = (ball == ~0ULL) ? 1 : 0;  // all-zero odd words => int64
}

__global__ void convert_kernel(const void* __restrict__ ei, const int* __restrict__ flag,
                               int* __restrict__ out, int n2e) {
    int i = blockIdx.x * blockDim.x + threadIdx.x;
    if (i >= n2e) return;
    if (*flag)
        out[i] = (int)((const long long*)ei)[i];
    else
        out[i] = ((const int*)ei)[i];
}

// ---------------------------------------------------------------------------
// gcn_norm: in-degree at dst, dinv = rsqrt(deg) (0 if deg==0),
// norm[e] = dinv[src]*dinv[dst]. Computed ONCE, reused for both convs.
// ---------------------------------------------------------------------------
__global__ void deg_kernel(const int* __restrict__ dst, int* __restrict__ deg, int E) {
    int e = blockIdx.x * blockDim.x + threadIdx.x;
    if (e < E) atomicAdd(&deg[dst[e]], 1);
}

__global__ void dinv_kernel(const int* __restrict__ deg, float* __restrict__ dinv, int n) {
    int i = blockIdx.x * blockDim.x + threadIdx.x;
    if (i < n) {
        int d = deg[i];
        dinv[i] = (d > 0) ? rsqrtf((float)d) : 0.0f;
    }
}

__global__ void norm_kernel(const int* __restrict__ src, const int* __restrict__ dst,
                            const float* __restrict__ dinv, float* __restrict__ norm, int E) {
    int e = blockIdx.x * blockDim.x + threadIdx.x;
    if (e < E) norm[e] = dinv[src[e]] * dinv[dst[e]];
}

// ---------------------------------------------------------------------------
// conv: one wave per edge, lane = feature. Gather x[src] (coalesced 256B/wave),
// scale by norm, atomicAdd into out[dst] (64 consecutive floats per wave).
// out must be pre-zeroed. relu is applied by the consumer on load.
// ---------------------------------------------------------------------------
__global__ __launch_bounds__(256) void conv_kernel(const float* __restrict__ x,
                                                   const int* __restrict__ src,
                                                   const int* __restrict__ dst,
                                                   const float* __restrict__ norm,
                                                   float* __restrict__ out, int E) {
    int gid = blockIdx.x * 256 + threadIdx.x;
    int e = gid >> 6;
    int f = gid & 63;
    if (e >= E) return;
    int s = src[e];
    int d = dst[e];
    float v = x[s * F + f] * norm[e];
    atomicAdd(&out[d * F + f], v);
}

// ---------------------------------------------------------------------------
// lin1: h2 = relu(relu(h1) @ W1 + b1).  One wave per row; lane holds h1[row,lane]
// in a register, broadcast via __shfl; W1 staged in LDS (16 KB).
// Applies relu on LOAD (input is raw conv sums) and relu on STORE.
// ---------------------------------------------------------------------------
__global__ __launch_bounds__(256) void lin1_kernel(const float* __restrict__ h,
                                                   const float* __restrict__ W1,
                                                   const float* __restrict__ b1,
                                                   float* __restrict__ out, int n) {
    __shared__ float Ws[F * F];
    for (int i = threadIdx.x; i < F * F; i += 256) Ws[i] = W1[i];
    __syncthreads();
    int gid = blockIdx.x * 256 + threadIdx.x;
    int row = gid >> 6;
    int f = threadIdx.x & 63;
    if (row >= n) return;
    float hv = fmaxf(h[row * F + f], 0.0f);   // relu on load
    float acc = b1[f];
#pragma unroll
    for (int k = 0; k < F; ++k) {
        acc = fmaf(__shfl(hv, k, 64), Ws[k * F + f], acc);
    }
    out[row * F + f] = fmaxf(acc, 0.0f);       // relu on store
}

// ---------------------------------------------------------------------------
// lin2 + log_softmax fused: one wave per row. lane c<47 computes the logit,
// then wave-reduce max / sum-exp across lanes, write log-probs.
// Applies relu on LOAD (input is raw conv2 sums).
// ---------------------------------------------------------------------------
__global__ __launch_bounds__(256) void lin2_kernel(const float* __restrict__ h,
                                                   const float* __restrict__ W2,
                                                   const float* __restrict__ b2,
                                                   float* __restrict__ out, int n) {
    __shared__ float Ws[F * 48];  // index k*47+c, c in [0,64): max 3024 < 3072
    for (int i = threadIdx.x; i < F * 48; i += 256)
        Ws[i] = (i < F * NC) ? W2[i] : 0.0f;
    __syncthreads();
    int row = blockIdx.x * 4 + (threadIdx.x >> 6);
    int c = threadIdx.x & 63;
    if (row >= n) return;
    float hv = fmaxf(h[row * F + c], 0.0f);    // relu on load
    float acc = (c < NC) ? b2[c] : 0.0f;
#pragma unroll
    for (int k = 0; k < F; ++k) {
        acc = fmaf(__shfl(hv, k, 64), Ws[k * NC + c], acc);
    }
    float m = (c < NC) ? acc : -INFINITY;
#pragma unroll
    for (int off = 32; off > 0; off >>= 1) m = fmaxf(m, __shfl_xor(m, off, 64));
    float ex = (c < NC) ? expf(acc - m) : 0.0f;
    float s = ex;
#pragma unroll
    for (int off = 32; off > 0; off >>= 1) s += __shfl_xor(s, off, 64);
    if (c < NC) out[row * NC + c] = acc - m - logf(s);
}

// ---------------------------------------------------------------------------
extern "C" void kernel_launch(void* const* d_in, const int* in_sizes, int n_in,
                              void* d_out, int out_size, void* d_ws, size_t ws_size,
                              hipStream_t stream) {
    const float* x  = (const float*)d_in[0];
    const void*  ei = d_in[1];
    const float* W1 = (const float*)d_in[2];
    const float* b1 = (const float*)d_in[3];
    const float* W2 = (const float*)d_in[4];
    const float* b2 = (const float*)d_in[5];
    float* out = (float*)d_out;

    const int E = in_sizes[1] / 2;
    const int n2e = in_sizes[1];

    // workspace carve-out (256B aligned)
    char* ws = (char*)d_ws;
    size_t off = 0;
    auto alloc = [&](size_t bytes) -> void* {
        void* p = ws + off;
        off = (off + bytes + 255) & ~(size_t)255;
        return p;
    };
    int*   flag  = (int*)  alloc(4);
    int*   deg   = (int*)  alloc((size_t)NN * 4);
    float* dinv  = (float*)alloc((size_t)NN * 4);
    float* norm  = (float*)alloc((size_t)E * 4);
    int*   e32   = (int*)  alloc((size_t)n2e * 4);   // src32 | dst32
    float* bufA  = (float*)alloc((size_t)NN * F * 4);
    float* bufB  = (float*)alloc((size_t)NN * F * 4);
    int* src32 = e32;
    int* dst32 = e32 + E;

    hipMemsetAsync(deg, 0, (size_t)NN * 4, stream);
    hipMemsetAsync(bufA, 0, (size_t)NN * F * 4, stream);

    detect_kernel<<<1, 64, 0, stream>>>(ei, flag);
    convert_kernel<<<(n2e + 255) / 256, 256, 0, stream>>>(ei, flag, e32, n2e);

    deg_kernel <<<(E + 255) / 256, 256, 0, stream>>>(dst32, deg, E);
    dinv_kernel<<<(NN + 255) / 256, 256, 0, stream>>>(deg, dinv, NN);
    norm_kernel<<<(E + 255) / 256, 256, 0, stream>>>(src32, dst32, dinv, norm, E);

    // conv1: x -> bufA (raw sums)
    int conv_blocks = (int)(((long long)E * 64 + 255) / 256);
    conv_kernel<<<conv_blocks, 256, 0, stream>>>(x, src32, dst32, norm, bufA, E);

    // lin1: relu(bufA) @ W1 + b1, relu -> bufB
    lin1_kernel<<<(NN * 64 + 255) / 256, 256, 0, stream>>>(bufA, W1, b1, bufB, NN);

    // conv2: bufB -> bufA (re-zeroed, raw sums)
    hipMemsetAsync(bufA, 0, (size_t)NN * F * 4, stream);
    conv_kernel<<<conv_blocks, 256, 0, stream>>>(bufB, src32, dst32, norm, bufA, E);

    // lin2 + log_softmax: relu(bufA) @ W2 + b2 -> out
    lin2_kernel<<<(NN + 3) / 4, 256, 0, stream>>>(bufA, W2, b2, out, NN);
}

// Round 2
// 573.445 us; speedup vs baseline: 1.7865x; 1.7865x over previous
//
#include <hip/hip_runtime.h>
#include <math.h>

#define NN 100000
#define F 64
#define NC 47
#define SCAN_BLK 1024   // elements per scan1 block (256 thr x 4)

// ---------------------------------------------------------------------------
// Edge dtype handling: harness may deliver edge_index as int32 or int64.
// ---------------------------------------------------------------------------
__global__ void detect_kernel(const void* __restrict__ ei, int* __restrict__ flag) {
    const int* e32 = (const int*)ei;
    int i = threadIdx.x;                 // 64 threads
    int v = e32[2 * i + 1];
    unsigned long long ball = __ballot(v == 0);
    if (i == 0) *flag = (ball == ~0ULL) ? 1 : 0;  // all-zero odd words => int64
}

__global__ void convert_kernel(const void* __restrict__ ei, const int* __restrict__ flag,
                               int* __restrict__ out, int n2e) {
    int i = blockIdx.x * blockDim.x + threadIdx.x;
    if (i >= n2e) return;
    if (*flag)
        out[i] = (int)((const long long*)ei)[i];
    else
        out[i] = ((const int*)ei)[i];
}

// ---------------------------------------------------------------------------
// degree + dinv
// ---------------------------------------------------------------------------
__global__ void deg_kernel(const int* __restrict__ dst, int* __restrict__ deg, int E) {
    int e = blockIdx.x * blockDim.x + threadIdx.x;
    if (e < E) atomicAdd(&deg[dst[e]], 1);
}

__global__ void dinv_kernel(const int* __restrict__ deg, float* __restrict__ dinv, int n) {
    int i = blockIdx.x * blockDim.x + threadIdx.x;
    if (i < n) {
        int d = deg[i];
        dinv[i] = (d > 0) ? rsqrtf((float)d) : 0.0f;
    }
}

// ---------------------------------------------------------------------------
// exclusive scan of deg -> rowptr (3 kernels; NN=100k => 98 blocks <= 256)
// ---------------------------------------------------------------------------
__global__ __launch_bounds__(256) void scan1_kernel(const int* __restrict__ deg,
                                                    int* __restrict__ excl,
                                                    int* __restrict__ bsum, int n) {
    __shared__ int lds[256];
    int t = threadIdx.x;
    int base = blockIdx.x * SCAN_BLK + t * 4;
    int v0 = (base + 0 < n) ? deg[base + 0] : 0;
    int v1 = (base + 1 < n) ? deg[base + 1] : 0;
    int v2 = (base + 2 < n) ? deg[base + 2] : 0;
    int v3 = (base + 3 < n) ? deg[base + 3] : 0;
    int s = v0 + v1 + v2 + v3;
    lds[t] = s;
    __syncthreads();
    for (int off = 1; off < 256; off <<= 1) {
        int a = (t >= off) ? lds[t - off] : 0;
        __syncthreads();
        lds[t] += a;
        __syncthreads();
    }
    int inc = lds[t];
    int exc = inc - s;
    if (t == 255) bsum[blockIdx.x] = inc;
    if (base + 0 < n) excl[base + 0] = exc;
    if (base + 1 < n) excl[base + 1] = exc + v0;
    if (base + 2 < n) excl[base + 2] = exc + v0 + v1;
    if (base + 3 < n) excl[base + 3] = exc + v0 + v1 + v2;
}

__global__ __launch_bounds__(256) void scan2_kernel(int* __restrict__ bsum, int nb) {
    __shared__ int lds[256];
    int t = threadIdx.x;
    int v = (t < nb) ? bsum[t] : 0;
    lds[t] = v;
    __syncthreads();
    for (int off = 1; off < 256; off <<= 1) {
        int a = (t >= off) ? lds[t - off] : 0;
        __syncthreads();
        lds[t] += a;
        __syncthreads();
    }
    if (t < nb) bsum[t] = lds[t] - v;   // exclusive
}

__global__ void scan3_kernel(const int* __restrict__ excl, const int* __restrict__ bsum,
                             int* __restrict__ rowptr, int* __restrict__ cursor,
                             int n, int E) {
    int i = blockIdx.x * blockDim.x + threadIdx.x;
    if (i >= n) return;
    int r = excl[i] + bsum[i >> 10];
    rowptr[i] = r;
    cursor[i] = r;
    if (i == 0) rowptr[n] = E;
}

// ---------------------------------------------------------------------------
// counting-sort scatter: edges bucketed by dst; payload = {src, norm_bits}
// ---------------------------------------------------------------------------
__global__ void scatter_kernel(const int* __restrict__ src, const int* __restrict__ dst,
                               const float* __restrict__ dinv, int* __restrict__ cursor,
                               int2* __restrict__ esort, int E) {
    int e = blockIdx.x * blockDim.x + threadIdx.x;
    if (e >= E) return;
    int s = src[e];
    int d = dst[e];
    float nm = dinv[s] * dinv[d];
    int pos = atomicAdd(&cursor[d], 1);
    esort[pos] = make_int2(s, __float_as_int(nm));
}

// ---------------------------------------------------------------------------
// CSR conv: one wave per node row, lane = feature. Batch-load 64 edge
// payloads coalesced, shfl-broadcast each, gather x[src], accumulate in
// register, single store. Output is the raw conv result (pre-relu).
// ---------------------------------------------------------------------------
__global__ __launch_bounds__(256) void conv_csr_kernel(const float* __restrict__ x,
                                                       const int* __restrict__ rowptr,
                                                       const int2* __restrict__ esort,
                                                       float* __restrict__ out, int n) {
    int row = blockIdx.x * 4 + (threadIdx.x >> 6);
    int f = threadIdx.x & 63;
    if (row >= n) return;
    int beg = rowptr[row];
    int end = rowptr[row + 1];
    float acc = 0.0f;
    for (int base = beg; base < end; base += 64) {
        int m = end - base;
        if (m > 64) m = 64;
        int2 ev = (f < m) ? esort[base + f] : make_int2(0, 0);
        for (int k = 0; k < m; ++k) {
            int s = __shfl(ev.x, k, 64);
            int w = __shfl(ev.y, k, 64);
            acc = fmaf(x[s * F + f], __int_as_float(w), acc);
        }
    }
    out[row * F + f] = acc;
}

// ---------------------------------------------------------------------------
// lin1: out = relu(relu(h) @ W1 + b1)
// ---------------------------------------------------------------------------
__global__ __launch_bounds__(256) void lin1_kernel(const float* __restrict__ h,
                                                   const float* __restrict__ W1,
                                                   const float* __restrict__ b1,
                                                   float* __restrict__ out, int n) {
    __shared__ float Ws[F * F];
    for (int i = threadIdx.x; i < F * F; i += 256) Ws[i] = W1[i];
    __syncthreads();
    int gid = blockIdx.x * 256 + threadIdx.x;
    int row = gid >> 6;
    int f = threadIdx.x & 63;
    if (row >= n) return;
    float hv = fmaxf(h[row * F + f], 0.0f);   // relu on load
    float acc = b1[f];
#pragma unroll
    for (int k = 0; k < F; ++k) {
        acc = fmaf(__shfl(hv, k, 64), Ws[k * F + f], acc);
    }
    out[row * F + f] = fmaxf(acc, 0.0f);       // relu on store
}

// ---------------------------------------------------------------------------
// lin2 + log_softmax fused
// ---------------------------------------------------------------------------
__global__ __launch_bounds__(256) void lin2_kernel(const float* __restrict__ h,
                                                   const float* __restrict__ W2,
                                                   const float* __restrict__ b2,
                                                   float* __restrict__ out, int n) {
    __shared__ float Ws[F * 48];
    for (int i = threadIdx.x; i < F * 48; i += 256)
        Ws[i] = (i < F * NC) ? W2[i] : 0.0f;
    __syncthreads();
    int row = blockIdx.x * 4 + (threadIdx.x >> 6);
    int c = threadIdx.x & 63;
    if (row >= n) return;
    float hv = fmaxf(h[row * F + c], 0.0f);    // relu on load
    float acc = (c < NC) ? b2[c] : 0.0f;
#pragma unroll
    for (int k = 0; k < F; ++k) {
        acc = fmaf(__shfl(hv, k, 64), Ws[k * NC + c], acc);
    }
    float m = (c < NC) ? acc : -INFINITY;
#pragma unroll
    for (int off = 32; off > 0; off >>= 1) m = fmaxf(m, __shfl_xor(m, off, 64));
    float ex = (c < NC) ? expf(acc - m) : 0.0f;
    float s = ex;
#pragma unroll
    for (int off = 32; off > 0; off >>= 1) s += __shfl_xor(s, off, 64);
    if (c < NC) out[row * NC + c] = acc - m - logf(s);
}

// ---------------------------------------------------------------------------
extern "C" void kernel_launch(void* const* d_in, const int* in_sizes, int n_in,
                              void* d_out, int out_size, void* d_ws, size_t ws_size,
                              hipStream_t stream) {
    const float* x  = (const float*)d_in[0];
    const void*  ei = d_in[1];
    const float* W1 = (const float*)d_in[2];
    const float* b1 = (const float*)d_in[3];
    const float* W2 = (const float*)d_in[4];
    const float* b2 = (const float*)d_in[5];
    float* out = (float*)d_out;

    const int E = in_sizes[1] / 2;
    const int n2e = in_sizes[1];
    const int NB = (NN + SCAN_BLK - 1) / SCAN_BLK;   // 98 <= 256

    // workspace carve-out (256B aligned)
    char* ws = (char*)d_ws;
    size_t off = 0;
    auto alloc = [&](size_t bytes) -> void* {
        void* p = ws + off;
        off = (off + bytes + 255) & ~(size_t)255;
        return p;
    };
    int*   flag   = (int*)  alloc(4);
    int*   deg    = (int*)  alloc((size_t)NN * 4);
    float* dinv   = (float*)alloc((size_t)NN * 4);
    int*   e32    = (int*)  alloc((size_t)n2e * 4);        // src32 | dst32
    int*   excl   = (int*)  alloc((size_t)NN * 4);
    int*   bsum   = (int*)  alloc(256 * 4);
    int*   rowptr = (int*)  alloc((size_t)(NN + 1) * 4);
    int*   cursor = (int*)  alloc((size_t)NN * 4);
    int2*  esort  = (int2*) alloc((size_t)E * 8);
    float* bufA   = (float*)alloc((size_t)NN * F * 4);
    float* bufB   = (float*)alloc((size_t)NN * F * 4);
    int* src32 = e32;
    int* dst32 = e32 + E;

    hipMemsetAsync(deg, 0, (size_t)NN * 4, stream);

    detect_kernel<<<1, 64, 0, stream>>>(ei, flag);
    convert_kernel<<<(n2e + 255) / 256, 256, 0, stream>>>(ei, flag, e32, n2e);

    deg_kernel <<<(E + 255) / 256, 256, 0, stream>>>(dst32, deg, E);
    dinv_kernel<<<(NN + 255) / 256, 256, 0, stream>>>(deg, dinv, NN);

    scan1_kernel<<<NB, 256, 0, stream>>>(deg, excl, bsum, NN);
    scan2_kernel<<<1, 256, 0, stream>>>(bsum, NB);
    scan3_kernel<<<(NN + 255) / 256, 256, 0, stream>>>(excl, bsum, rowptr, cursor, NN, E);

    scatter_kernel<<<(E + 255) / 256, 256, 0, stream>>>(src32, dst32, dinv, cursor, esort, E);

    // conv1: x -> bufA (raw conv sums)
    conv_csr_kernel<<<(NN + 3) / 4, 256, 0, stream>>>(x, rowptr, esort, bufA, NN);

    // lin1: relu(bufA) @ W1 + b1, relu -> bufB
    lin1_kernel<<<(NN * 64 + 255) / 256, 256, 0, stream>>>(bufA, W1, b1, bufB, NN);

    // conv2: bufB -> bufA (raw conv sums)
    conv_csr_kernel<<<(NN + 3) / 4, 256, 0, stream>>>(bufB, rowptr, esort, bufA, NN);

    // lin2 + log_softmax: relu(bufA) @ W2 + b2 -> out
    lin2_kernel<<<(NN + 3) / 4, 256, 0, stream>>>(bufA, W2, b2, out, NN);
}

// Round 3
// 500.066 us; speedup vs baseline: 2.0487x; 1.1467x over previous
//
#include <hip/hip_runtime.h>
#include <math.h>

#define NN 100000
#define F 64
#define NC 47
#define SCAN_BLK 1024   // elements per scan1 block (256 thr x 4)

// ---------------------------------------------------------------------------
// Edge dtype handling: harness may deliver edge_index as int32 or int64.
// ---------------------------------------------------------------------------
__global__ void detect_kernel(const void* __restrict__ ei, int* __restrict__ flag) {
    const int* e32 = (const int*)ei;
    int i = threadIdx.x;                 // 64 threads
    int v = e32[2 * i + 1];
    unsigned long long ball = __ballot(v == 0);
    if (i == 0) *flag = (ball == ~0ULL) ? 1 : 0;  // all-zero odd words => int64
}

__global__ void convert_kernel(const void* __restrict__ ei, const int* __restrict__ flag,
                               int* __restrict__ out, int n2e) {
    int i = blockIdx.x * blockDim.x + threadIdx.x;
    if (i >= n2e) return;
    if (*flag)
        out[i] = (int)((const long long*)ei)[i];
    else
        out[i] = ((const int*)ei)[i];
}

// ---------------------------------------------------------------------------
// degree + dinv
// ---------------------------------------------------------------------------
__global__ void deg_kernel(const int* __restrict__ dst, int* __restrict__ deg, int E) {
    int e = blockIdx.x * blockDim.x + threadIdx.x;
    if (e < E) atomicAdd(&deg[dst[e]], 1);
}

__global__ void dinv_kernel(const int* __restrict__ deg, float* __restrict__ dinv, int n) {
    int i = blockIdx.x * blockDim.x + threadIdx.x;
    if (i < n) {
        int d = deg[i];
        dinv[i] = (d > 0) ? rsqrtf((float)d) : 0.0f;
    }
}

// ---------------------------------------------------------------------------
// exclusive scan of deg -> rowptr
// ---------------------------------------------------------------------------
__global__ __launch_bounds__(256) void scan1_kernel(const int* __restrict__ deg,
                                                    int* __restrict__ excl,
                                                    int* __restrict__ bsum, int n) {
    __shared__ int lds[256];
    int t = threadIdx.x;
    int base = blockIdx.x * SCAN_BLK + t * 4;
    int v0 = (base + 0 < n) ? deg[base + 0] : 0;
    int v1 = (base + 1 < n) ? deg[base + 1] : 0;
    int v2 = (base + 2 < n) ? deg[base + 2] : 0;
    int v3 = (base + 3 < n) ? deg[base + 3] : 0;
    int s = v0 + v1 + v2 + v3;
    lds[t] = s;
    __syncthreads();
    for (int off = 1; off < 256; off <<= 1) {
        int a = (t >= off) ? lds[t - off] : 0;
        __syncthreads();
        lds[t] += a;
        __syncthreads();
    }
    int inc = lds[t];
    int exc = inc - s;
    if (t == 255) bsum[blockIdx.x] = inc;
    if (base + 0 < n) excl[base + 0] = exc;
    if (base + 1 < n) excl[base + 1] = exc + v0;
    if (base + 2 < n) excl[base + 2] = exc + v0 + v1;
    if (base + 3 < n) excl[base + 3] = exc + v0 + v1 + v2;
}

__global__ __launch_bounds__(256) void scan2_kernel(int* __restrict__ bsum, int nb) {
    __shared__ int lds[256];
    int t = threadIdx.x;
    int v = (t < nb) ? bsum[t] : 0;
    lds[t] = v;
    __syncthreads();
    for (int off = 1; off < 256; off <<= 1) {
        int a = (t >= off) ? lds[t - off] : 0;
        __syncthreads();
        lds[t] += a;
        __syncthreads();
    }
    if (t < nb) bsum[t] = lds[t] - v;   // exclusive
}

__global__ void scan3_kernel(const int* __restrict__ excl, const int* __restrict__ bsum,
                             int* __restrict__ rowptr, int* __restrict__ cursor,
                             int n, int E) {
    int i = blockIdx.x * blockDim.x + threadIdx.x;
    if (i >= n) return;
    int r = excl[i] + bsum[i >> 10];
    rowptr[i] = r;
    cursor[i] = r;
    if (i == 0) rowptr[n] = E;
}

// ---------------------------------------------------------------------------
// counting-sort scatter: edges bucketed by dst; payload = {src, norm_bits}
// ---------------------------------------------------------------------------
__global__ void scatter_kernel(const int* __restrict__ src, const int* __restrict__ dst,
                               const float* __restrict__ dinv, int* __restrict__ cursor,
                               int2* __restrict__ esort, int E) {
    int e = blockIdx.x * blockDim.x + threadIdx.x;
    if (e >= E) return;
    int s = src[e];
    int d = dst[e];
    float nm = dinv[s] * dinv[d];
    int pos = atomicAdd(&cursor[d], 1);
    esort[pos] = make_int2(s, __float_as_int(nm));
}

// ---------------------------------------------------------------------------
// CSR conv: one wave per node row, lane = feature. 4-wide unrolled inner loop
// issues 4 independent gathers back-to-back for memory-level parallelism.
// ---------------------------------------------------------------------------
__global__ __launch_bounds__(256) void conv_csr_kernel(const float* __restrict__ x,
                                                       const int* __restrict__ rowptr,
                                                       const int2* __restrict__ esort,
                                                       float* __restrict__ out, int n) {
    int row = blockIdx.x * 4 + (threadIdx.x >> 6);
    int f = threadIdx.x & 63;
    if (row >= n) return;
    int beg = rowptr[row];
    int end = rowptr[row + 1];
    float acc = 0.0f;
    for (int base = beg; base < end; base += 64) {
        int rem = end - base;
        int m = rem > 64 ? 64 : rem;
        int2 ev = (f < m) ? esort[base + f] : make_int2(0, 0);
        int k = 0;
        for (; k + 4 <= m; k += 4) {
            int s0 = __shfl(ev.x, k, 64),     w0 = __shfl(ev.y, k, 64);
            int s1 = __shfl(ev.x, k + 1, 64), w1 = __shfl(ev.y, k + 1, 64);
            int s2 = __shfl(ev.x, k + 2, 64), w2 = __shfl(ev.y, k + 2, 64);
            int s3 = __shfl(ev.x, k + 3, 64), w3 = __shfl(ev.y, k + 3, 64);
            float v0 = x[(size_t)s0 * F + f];
            float v1 = x[(size_t)s1 * F + f];
            float v2 = x[(size_t)s2 * F + f];
            float v3 = x[(size_t)s3 * F + f];
            acc = fmaf(v0, __int_as_float(w0), acc);
            acc = fmaf(v1, __int_as_float(w1), acc);
            acc = fmaf(v2, __int_as_float(w2), acc);
            acc = fmaf(v3, __int_as_float(w3), acc);
        }
        for (; k < m; ++k) {
            int s = __shfl(ev.x, k, 64), w = __shfl(ev.y, k, 64);
            acc = fmaf(x[(size_t)s * F + f], __int_as_float(w), acc);
        }
    }
    out[row * F + f] = acc;
}

// ---------------------------------------------------------------------------
// Register-tiled lin kernels. Block = 256 threads = 64-row tile.
// Thread (ty = t>>4, tx = t&15) owns rows 4ty..4ty+3, cols {tx, tx+16, tx+32, tx+48}.
// W transposed into LDS with XOR swizzle slot = kq ^ (c&7)  (c&7 == tx&7 for all
// 4 col-groups -> ds_read_b128 <=2-way bank aliasing = free).
// h fragments read directly from global as 16-lane-broadcast float4 (L2/L3-hot).
// relu applied on load (inputs are raw conv sums).
// ---------------------------------------------------------------------------
__device__ __forceinline__ float4 relu4(float4 v) {
    v.x = fmaxf(v.x, 0.0f); v.y = fmaxf(v.y, 0.0f);
    v.z = fmaxf(v.z, 0.0f); v.w = fmaxf(v.w, 0.0f);
    return v;
}

__global__ __launch_bounds__(256) void lin1_kernel(const float* __restrict__ h,
                                                   const float* __restrict__ W1,
                                                   const float* __restrict__ b1,
                                                   float* __restrict__ out, int n) {
    __shared__ float wt[64 * 64];   // wt4[c][kq^(c&7)] layout
    int t = threadIdx.x;
    for (int i = t; i < 64 * 64; i += 256) {
        int k = i >> 6, c = i & 63;
        int kq = k >> 2, slot = kq ^ (c & 7);
        wt[c * 64 + slot * 4 + (k & 3)] = W1[i];
    }
    __syncthreads();
    const float4* wt4 = (const float4*)wt;
    const float4* h4 = (const float4*)h;

    int tx = t & 15, ty = t >> 4;
    int r0 = blockIdx.x * 64 + 4 * ty;          // first of 4 rows
    float acc[4][4] = {};
#pragma unroll
    for (int kq = 0; kq < 16; ++kq) {
        int slot = kq ^ (tx & 7);
        float4 b0 = wt4[(tx +  0) * 16 + slot];
        float4 b1v = wt4[(tx + 16) * 16 + slot];
        float4 b2v = wt4[(tx + 32) * 16 + slot];
        float4 b3v = wt4[(tx + 48) * 16 + slot];
#pragma unroll
        for (int i = 0; i < 4; ++i) {
            int r = r0 + i;
            float4 a = (r < n) ? relu4(h4[(size_t)r * 16 + kq])
                               : make_float4(0.f, 0.f, 0.f, 0.f);
            acc[i][0] = fmaf(a.x, b0.x,  fmaf(a.y, b0.y,  fmaf(a.z, b0.z,  fmaf(a.w, b0.w,  acc[i][0]))));
            acc[i][1] = fmaf(a.x, b1v.x, fmaf(a.y, b1v.y, fmaf(a.z, b1v.z, fmaf(a.w, b1v.w, acc[i][1]))));
            acc[i][2] = fmaf(a.x, b2v.x, fmaf(a.y, b2v.y, fmaf(a.z, b2v.z, fmaf(a.w, b2v.w, acc[i][2]))));
            acc[i][3] = fmaf(a.x, b3v.x, fmaf(a.y, b3v.y, fmaf(a.z, b3v.z, fmaf(a.w, b3v.w, acc[i][3]))));
        }
    }
    float bj[4];
#pragma unroll
    for (int g = 0; g < 4; ++g) bj[g] = b1[tx + 16 * g];
#pragma unroll
    for (int i = 0; i < 4; ++i) {
        int r = r0 + i;
        if (r >= n) break;
#pragma unroll
        for (int g = 0; g < 4; ++g)
            out[(size_t)r * 64 + tx + 16 * g] = fmaxf(acc[i][g] + bj[g], 0.0f);
    }
}

__global__ __launch_bounds__(256) void lin2_kernel(const float* __restrict__ h,
                                                   const float* __restrict__ W2,
                                                   const float* __restrict__ b2,
                                                   float* __restrict__ out, int n) {
    __shared__ float wt[64 * 64];   // cols >= 47 zero-padded
    int t = threadIdx.x;
    for (int i = t; i < 64 * 64; i += 256) {
        int k = i >> 6, c = i & 63;
        int kq = k >> 2, slot = kq ^ (c & 7);
        wt[c * 64 + slot * 4 + (k & 3)] = (c < NC) ? W2[k * NC + c] : 0.0f;
    }
    __syncthreads();
    const float4* wt4 = (const float4*)wt;
    const float4* h4 = (const float4*)h;

    int tx = t & 15, ty = t >> 4;
    int r0 = blockIdx.x * 64 + 4 * ty;
    float acc[4][4] = {};
#pragma unroll
    for (int kq = 0; kq < 16; ++kq) {
        int slot = kq ^ (tx & 7);
        float4 b0 = wt4[(tx +  0) * 16 + slot];
        float4 b1v = wt4[(tx + 16) * 16 + slot];
        float4 b2v = wt4[(tx + 32) * 16 + slot];
        float4 b3v = wt4[(tx + 48) * 16 + slot];
#pragma unroll
        for (int i = 0; i < 4; ++i) {
            int r = r0 + i;
            float4 a = (r < n) ? relu4(h4[(size_t)r * 16 + kq])
                               : make_float4(0.f, 0.f, 0.f, 0.f);
            acc[i][0] = fmaf(a.x, b0.x,  fmaf(a.y, b0.y,  fmaf(a.z, b0.z,  fmaf(a.w, b0.w,  acc[i][0]))));
            acc[i][1] = fmaf(a.x, b1v.x, fmaf(a.y, b1v.y, fmaf(a.z, b1v.z, fmaf(a.w, b1v.w, acc[i][1]))));
            acc[i][2] = fmaf(a.x, b2v.x, fmaf(a.y, b2v.y, fmaf(a.z, b2v.z, fmaf(a.w, b2v.w, acc[i][2]))));
            acc[i][3] = fmaf(a.x, b3v.x, fmaf(a.y, b3v.y, fmaf(a.z, b3v.z, fmaf(a.w, b3v.w, acc[i][3]))));
        }
    }
    // add bias; cols c = tx+16g valid iff c < 47 (g==3 never valid)
    bool vm[4];
    float bj[4];
#pragma unroll
    for (int g = 0; g < 4; ++g) {
        int c = tx + 16 * g;
        vm[g] = (c < NC);
        bj[g] = vm[g] ? b2[c] : 0.0f;
    }
#pragma unroll
    for (int i = 0; i < 4; ++i) {
        int r = r0 + i;
        float v[4];
        float m = -INFINITY;
#pragma unroll
        for (int g = 0; g < 4; ++g) {
            v[g] = acc[i][g] + bj[g];
            if (vm[g]) m = fmaxf(m, v[g]);
        }
#pragma unroll
        for (int off = 8; off > 0; off >>= 1) m = fmaxf(m, __shfl_xor(m, off, 64));
        float s = 0.0f;
#pragma unroll
        for (int g = 0; g < 4; ++g)
            if (vm[g]) s += expf(v[g] - m);
#pragma unroll
        for (int off = 8; off > 0; off >>= 1) s += __shfl_xor(s, off, 64);
        float lse = m + logf(s);
        if (r < n) {
#pragma unroll
            for (int g = 0; g < 4; ++g)
                if (vm[g]) out[(size_t)r * NC + tx + 16 * g] = v[g] - lse;
        }
    }
}

// ---------------------------------------------------------------------------
extern "C" void kernel_launch(void* const* d_in, const int* in_sizes, int n_in,
                              void* d_out, int out_size, void* d_ws, size_t ws_size,
                              hipStream_t stream) {
    const float* x  = (const float*)d_in[0];
    const void*  ei = d_in[1];
    const float* W1 = (const float*)d_in[2];
    const float* b1 = (const float*)d_in[3];
    const float* W2 = (const float*)d_in[4];
    const float* b2 = (const float*)d_in[5];
    float* out = (float*)d_out;

    const int E = in_sizes[1] / 2;
    const int n2e = in_sizes[1];
    const int NB = (NN + SCAN_BLK - 1) / SCAN_BLK;   // 98 <= 256

    // workspace carve-out (256B aligned)
    char* ws = (char*)d_ws;
    size_t off = 0;
    auto alloc = [&](size_t bytes) -> void* {
        void* p = ws + off;
        off = (off + bytes + 255) & ~(size_t)255;
        return p;
    };
    int*   flag   = (int*)  alloc(4);
    int*   deg    = (int*)  alloc((size_t)NN * 4);
    float* dinv   = (float*)alloc((size_t)NN * 4);
    int*   e32    = (int*)  alloc((size_t)n2e * 4);        // src32 | dst32
    int*   excl   = (int*)  alloc((size_t)NN * 4);
    int*   bsum   = (int*)  alloc(256 * 4);
    int*   rowptr = (int*)  alloc((size_t)(NN + 1) * 4);
    int*   cursor = (int*)  alloc((size_t)NN * 4);
    int2*  esort  = (int2*) alloc((size_t)E * 8);
    float* bufA   = (float*)alloc((size_t)NN * F * 4);
    float* bufB   = (float*)alloc((size_t)NN * F * 4);
    int* src32 = e32;
    int* dst32 = e32 + E;

    hipMemsetAsync(deg, 0, (size_t)NN * 4, stream);

    detect_kernel<<<1, 64, 0, stream>>>(ei, flag);
    convert_kernel<<<(n2e + 255) / 256, 256, 0, stream>>>(ei, flag, e32, n2e);

    deg_kernel <<<(E + 255) / 256, 256, 0, stream>>>(dst32, deg, E);
    dinv_kernel<<<(NN + 255) / 256, 256, 0, stream>>>(deg, dinv, NN);

    scan1_kernel<<<NB, 256, 0, stream>>>(deg, excl, bsum, NN);
    scan2_kernel<<<1, 256, 0, stream>>>(bsum, NB);
    scan3_kernel<<<(NN + 255) / 256, 256, 0, stream>>>(excl, bsum, rowptr, cursor, NN, E);

    scatter_kernel<<<(E + 255) / 256, 256, 0, stream>>>(src32, dst32, dinv, cursor, esort, E);

    const int lin_blocks = (NN + 63) / 64;   // 1563

    // conv1: x -> bufA (raw conv sums)
    conv_csr_kernel<<<(NN + 3) / 4, 256, 0, stream>>>(x, rowptr, esort, bufA, NN);

    // lin1: relu(bufA) @ W1 + b1, relu -> bufB
    lin1_kernel<<<lin_blocks, 256, 0, stream>>>(bufA, W1, b1, bufB, NN);

    // conv2: bufB -> bufA (raw conv sums)
    conv_csr_kernel<<<(NN + 3) / 4, 256, 0, stream>>>(bufB, rowptr, esort, bufA, NN);

    // lin2 + log_softmax: relu(bufA) @ W2 + b2 -> out
    lin2_kernel<<<lin_blocks, 256, 0, stream>>>(bufA, W2, b2, out, NN);
}

// Round 4
// 343.206 us; speedup vs baseline: 2.9850x; 1.4570x over previous
//
#include <hip/hip_runtime.h>
#include <math.h>

#define NN 100000
#define F 64
#define NC 47
#define SCAN_BLK 1024   // elements per scan1 block (256 thr x 4)

// ---------------------------------------------------------------------------
// Edge dtype handling: harness may deliver edge_index as int32 or int64.
// ---------------------------------------------------------------------------
__global__ void detect_kernel(const void* __restrict__ ei, int* __restrict__ flag) {
    const int* e32 = (const int*)ei;
    int i = threadIdx.x;                 // 64 threads
    int v = e32[2 * i + 1];
    unsigned long long ball = __ballot(v == 0);
    if (i == 0) *flag = (ball == ~0ULL) ? 1 : 0;  // all-zero odd words => int64
}

__global__ void convert_kernel(const void* __restrict__ ei, const int* __restrict__ flag,
                               int* __restrict__ out, int n2e) {
    int i = blockIdx.x * blockDim.x + threadIdx.x;
    if (i >= n2e) return;
    if (*flag)
        out[i] = (int)((const long long*)ei)[i];
    else
        out[i] = ((const int*)ei)[i];
}

// ---------------------------------------------------------------------------
// degree + dinv
// ---------------------------------------------------------------------------
__global__ void deg_kernel(const int* __restrict__ dst, int* __restrict__ deg, int E) {
    int e = blockIdx.x * blockDim.x + threadIdx.x;
    if (e < E) atomicAdd(&deg[dst[e]], 1);
}

__global__ void dinv_kernel(const int* __restrict__ deg, float* __restrict__ dinv, int n) {
    int i = blockIdx.x * blockDim.x + threadIdx.x;
    if (i < n) {
        int d = deg[i];
        dinv[i] = (d > 0) ? rsqrtf((float)d) : 0.0f;
    }
}

// ---------------------------------------------------------------------------
// exclusive scan of deg -> rowptr
// ---------------------------------------------------------------------------
__global__ __launch_bounds__(256) void scan1_kernel(const int* __restrict__ deg,
                                                    int* __restrict__ excl,
                                                    int* __restrict__ bsum, int n) {
    __shared__ int lds[256];
    int t = threadIdx.x;
    int base = blockIdx.x * SCAN_BLK + t * 4;
    int v0 = (base + 0 < n) ? deg[base + 0] : 0;
    int v1 = (base + 1 < n) ? deg[base + 1] : 0;
    int v2 = (base + 2 < n) ? deg[base + 2] : 0;
    int v3 = (base + 3 < n) ? deg[base + 3] : 0;
    int s = v0 + v1 + v2 + v3;
    lds[t] = s;
    __syncthreads();
    for (int off = 1; off < 256; off <<= 1) {
        int a = (t >= off) ? lds[t - off] : 0;
        __syncthreads();
        lds[t] += a;
        __syncthreads();
    }
    int inc = lds[t];
    int exc = inc - s;
    if (t == 255) bsum[blockIdx.x] = inc;
    if (base + 0 < n) excl[base + 0] = exc;
    if (base + 1 < n) excl[base + 1] = exc + v0;
    if (base + 2 < n) excl[base + 2] = exc + v0 + v1;
    if (base + 3 < n) excl[base + 3] = exc + v0 + v1 + v2;
}

__global__ __launch_bounds__(256) void scan2_kernel(int* __restrict__ bsum, int nb) {
    __shared__ int lds[256];
    int t = threadIdx.x;
    int v = (t < nb) ? bsum[t] : 0;
    lds[t] = v;
    __syncthreads();
    for (int off = 1; off < 256; off <<= 1) {
        int a = (t >= off) ? lds[t - off] : 0;
        __syncthreads();
        lds[t] += a;
        __syncthreads();
    }
    if (t < nb) bsum[t] = lds[t] - v;   // exclusive
}

__global__ void scan3_kernel(const int* __restrict__ excl, const int* __restrict__ bsum,
                             int* __restrict__ rowptr, int* __restrict__ cursor,
                             int n, int E) {
    int i = blockIdx.x * blockDim.x + threadIdx.x;
    if (i >= n) return;
    int r = excl[i] + bsum[i >> 10];
    rowptr[i] = r;
    cursor[i] = r;
    if (i == 0) rowptr[n] = E;
}

// ---------------------------------------------------------------------------
// counting-sort scatter: edges bucketed by dst; payload = {src, norm_bits}
// ---------------------------------------------------------------------------
__global__ void scatter_kernel(const int* __restrict__ src, const int* __restrict__ dst,
                               const float* __restrict__ dinv, int* __restrict__ cursor,
                               int2* __restrict__ esort, int E) {
    int e = blockIdx.x * blockDim.x + threadIdx.x;
    if (e >= E) return;
    int s = src[e];
    int d = dst[e];
    float nm = dinv[s] * dinv[d];
    int pos = atomicAdd(&cursor[d], 1);
    esort[pos] = make_int2(s, __float_as_int(nm));
}

// ---------------------------------------------------------------------------
// CSR conv: one wave per node row, lane = feature. 4-wide unrolled inner loop
// issues 4 independent gathers back-to-back for memory-level parallelism.
// ---------------------------------------------------------------------------
__global__ __launch_bounds__(256) void conv_csr_kernel(const float* __restrict__ x,
                                                       const int* __restrict__ rowptr,
                                                       const int2* __restrict__ esort,
                                                       float* __restrict__ out, int n) {
    int row = blockIdx.x * 4 + (threadIdx.x >> 6);
    int f = threadIdx.x & 63;
    if (row >= n) return;
    int beg = rowptr[row];
    int end = rowptr[row + 1];
    float acc = 0.0f;
    for (int base = beg; base < end; base += 64) {
        int rem = end - base;
        int m = rem > 64 ? 64 : rem;
        int2 ev = (f < m) ? esort[base + f] : make_int2(0, 0);
        int k = 0;
        for (; k + 4 <= m; k += 4) {
            int s0 = __shfl(ev.x, k, 64),     w0 = __shfl(ev.y, k, 64);
            int s1 = __shfl(ev.x, k + 1, 64), w1 = __shfl(ev.y, k + 1, 64);
            int s2 = __shfl(ev.x, k + 2, 64), w2 = __shfl(ev.y, k + 2, 64);
            int s3 = __shfl(ev.x, k + 3, 64), w3 = __shfl(ev.y, k + 3, 64);
            float v0 = x[(size_t)s0 * F + f];
            float v1 = x[(size_t)s1 * F + f];
            float v2 = x[(size_t)s2 * F + f];
            float v3 = x[(size_t)s3 * F + f];
            acc = fmaf(v0, __int_as_float(w0), acc);
            acc = fmaf(v1, __int_as_float(w1), acc);
            acc = fmaf(v2, __int_as_float(w2), acc);
            acc = fmaf(v3, __int_as_float(w3), acc);
        }
        for (; k < m; ++k) {
            int s = __shfl(ev.x, k, 64), w = __shfl(ev.y, k, 64);
            acc = fmaf(x[(size_t)s * F + f], __int_as_float(w), acc);
        }
    }
    out[row * F + f] = acc;
}

// ---------------------------------------------------------------------------
// Register-tiled lin kernels, v2: BOTH operands staged in LDS.
// Block = 256 threads = 64-row tile. Thread (ty=t>>4, tx=t&15) owns
// rows 4ty..4ty+3, cols {tx, tx+16, tx+32, tx+48}.
//   W LDS: wt4[c][kq ^ (tx&7)]  -> b-frag reads 8 groups x 2-way = free
//   h LDS: ht4[r][kq ^ ((r>>2)&7)] -> a-frag reads 8 groups x 2-way = free
//          (r>>2 == ty for the owned rows; staging writes also hit min cycles)
// #pragma unroll 2 caps in-flight fragments -> VGPR ~100, 4 blocks/CU.
// relu applied when staging h (inputs are raw conv sums).
// ---------------------------------------------------------------------------
__device__ __forceinline__ float4 relu4(float4 v) {
    v.x = fmaxf(v.x, 0.0f); v.y = fmaxf(v.y, 0.0f);
    v.z = fmaxf(v.z, 0.0f); v.w = fmaxf(v.w, 0.0f);
    return v;
}

__global__ __launch_bounds__(256) void lin1_kernel(const float* __restrict__ h,
                                                   const float* __restrict__ W1,
                                                   const float* __restrict__ b1,
                                                   float* __restrict__ out, int n) {
    __shared__ float wt[64 * 64];
    __shared__ float ht[64 * 64];
    int t = threadIdx.x;
    for (int i = t; i < 64 * 64; i += 256) {
        int k = i >> 6, c = i & 63;
        int kq = k >> 2, slot = kq ^ (c & 7);
        wt[c * 64 + slot * 4 + (k & 3)] = W1[i];
    }
    int row0 = blockIdx.x * 64;
    const float4* h4 = (const float4*)h;
    float4* ht4 = (float4*)ht;
#pragma unroll
    for (int j = 0; j < 4; ++j) {
        int flat = t + 256 * j;          // 0..1023 float4s of the tile
        int r = flat >> 4;
        int kq = flat & 15;
        int gr = row0 + r;
        float4 v = (gr < n) ? relu4(h4[(size_t)gr * 16 + kq])
                            : make_float4(0.f, 0.f, 0.f, 0.f);
        ht4[r * 16 + (kq ^ ((r >> 2) & 7))] = v;
    }
    __syncthreads();
    const float4* wt4 = (const float4*)wt;
    const float4* ht4c = (const float4*)ht;

    int tx = t & 15, ty = t >> 4;
    float acc[4][4] = {};
#pragma unroll 2
    for (int kq = 0; kq < 16; ++kq) {
        int wslot = kq ^ (tx & 7);
        float4 b0 = wt4[(tx +  0) * 16 + wslot];
        float4 b1v = wt4[(tx + 16) * 16 + wslot];
        float4 b2v = wt4[(tx + 32) * 16 + wslot];
        float4 b3v = wt4[(tx + 48) * 16 + wslot];
        int aslot = kq ^ (ty & 7);
#pragma unroll
        for (int i = 0; i < 4; ++i) {
            float4 a = ht4c[(4 * ty + i) * 16 + aslot];
            acc[i][0] = fmaf(a.x, b0.x,  fmaf(a.y, b0.y,  fmaf(a.z, b0.z,  fmaf(a.w, b0.w,  acc[i][0]))));
            acc[i][1] = fmaf(a.x, b1v.x, fmaf(a.y, b1v.y, fmaf(a.z, b1v.z, fmaf(a.w, b1v.w, acc[i][1]))));
            acc[i][2] = fmaf(a.x, b2v.x, fmaf(a.y, b2v.y, fmaf(a.z, b2v.z, fmaf(a.w, b2v.w, acc[i][2]))));
            acc[i][3] = fmaf(a.x, b3v.x, fmaf(a.y, b3v.y, fmaf(a.z, b3v.z, fmaf(a.w, b3v.w, acc[i][3]))));
        }
    }
    float bj[4];
#pragma unroll
    for (int g = 0; g < 4; ++g) bj[g] = b1[tx + 16 * g];
    int r0 = row0 + 4 * ty;
#pragma unroll
    for (int i = 0; i < 4; ++i) {
        int r = r0 + i;
        if (r >= n) break;
#pragma unroll
        for (int g = 0; g < 4; ++g)
            out[(size_t)r * 64 + tx + 16 * g] = fmaxf(acc[i][g] + bj[g], 0.0f);
    }
}

__global__ __launch_bounds__(256) void lin2_kernel(const float* __restrict__ h,
                                                   const float* __restrict__ W2,
                                                   const float* __restrict__ b2,
                                                   float* __restrict__ out, int n) {
    __shared__ float wt[64 * 64];   // cols >= 47 zero-padded
    __shared__ float ht[64 * 64];
    int t = threadIdx.x;
    for (int i = t; i < 64 * 64; i += 256) {
        int k = i >> 6, c = i & 63;
        int kq = k >> 2, slot = kq ^ (c & 7);
        wt[c * 64 + slot * 4 + (k & 3)] = (c < NC) ? W2[k * NC + c] : 0.0f;
    }
    int row0 = blockIdx.x * 64;
    const float4* h4 = (const float4*)h;
    float4* ht4 = (float4*)ht;
#pragma unroll
    for (int j = 0; j < 4; ++j) {
        int flat = t + 256 * j;
        int r = flat >> 4;
        int kq = flat & 15;
        int gr = row0 + r;
        float4 v = (gr < n) ? relu4(h4[(size_t)gr * 16 + kq])
                            : make_float4(0.f, 0.f, 0.f, 0.f);
        ht4[r * 16 + (kq ^ ((r >> 2) & 7))] = v;
    }
    __syncthreads();
    const float4* wt4 = (const float4*)wt;
    const float4* ht4c = (const float4*)ht;

    int tx = t & 15, ty = t >> 4;
    float acc[4][4] = {};
#pragma unroll 2
    for (int kq = 0; kq < 16; ++kq) {
        int wslot = kq ^ (tx & 7);
        float4 b0 = wt4[(tx +  0) * 16 + wslot];
        float4 b1v = wt4[(tx + 16) * 16 + wslot];
        float4 b2v = wt4[(tx + 32) * 16 + wslot];
        float4 b3v = wt4[(tx + 48) * 16 + wslot];
        int aslot = kq ^ (ty & 7);
#pragma unroll
        for (int i = 0; i < 4; ++i) {
            float4 a = ht4c[(4 * ty + i) * 16 + aslot];
            acc[i][0] = fmaf(a.x, b0.x,  fmaf(a.y, b0.y,  fmaf(a.z, b0.z,  fmaf(a.w, b0.w,  acc[i][0]))));
            acc[i][1] = fmaf(a.x, b1v.x, fmaf(a.y, b1v.y, fmaf(a.z, b1v.z, fmaf(a.w, b1v.w, acc[i][1]))));
            acc[i][2] = fmaf(a.x, b2v.x, fmaf(a.y, b2v.y, fmaf(a.z, b2v.z, fmaf(a.w, b2v.w, acc[i][2]))));
            acc[i][3] = fmaf(a.x, b3v.x, fmaf(a.y, b3v.y, fmaf(a.z, b3v.z, fmaf(a.w, b3v.w, acc[i][3]))));
        }
    }
    // bias; cols c = tx+16g valid iff c < 47 (g==3 never valid)
    bool vm[4];
    float bj[4];
#pragma unroll
    for (int g = 0; g < 4; ++g) {
        int c = tx + 16 * g;
        vm[g] = (c < NC);
        bj[g] = vm[g] ? b2[c] : 0.0f;
    }
    int r0 = row0 + 4 * ty;
#pragma unroll
    for (int i = 0; i < 4; ++i) {
        int r = r0 + i;
        float v[4];
        float m = -INFINITY;
#pragma unroll
        for (int g = 0; g < 4; ++g) {
            v[g] = acc[i][g] + bj[g];
            if (vm[g]) m = fmaxf(m, v[g]);
        }
#pragma unroll
        for (int off = 8; off > 0; off >>= 1) m = fmaxf(m, __shfl_xor(m, off, 64));
        float s = 0.0f;
#pragma unroll
        for (int g = 0; g < 4; ++g)
            if (vm[g]) s += expf(v[g] - m);
#pragma unroll
        for (int off = 8; off > 0; off >>= 1) s += __shfl_xor(s, off, 64);
        float lse = m + logf(s);
        if (r < n) {
#pragma unroll
            for (int g = 0; g < 4; ++g)
                if (vm[g]) out[(size_t)r * NC + tx + 16 * g] = v[g] - lse;
        }
    }
}

// ---------------------------------------------------------------------------
extern "C" void kernel_launch(void* const* d_in, const int* in_sizes, int n_in,
                              void* d_out, int out_size, void* d_ws, size_t ws_size,
                              hipStream_t stream) {
    const float* x  = (const float*)d_in[0];
    const void*  ei = d_in[1];
    const float* W1 = (const float*)d_in[2];
    const float* b1 = (const float*)d_in[3];
    const float* W2 = (const float*)d_in[4];
    const float* b2 = (const float*)d_in[5];
    float* out = (float*)d_out;

    const int E = in_sizes[1] / 2;
    const int n2e = in_sizes[1];
    const int NB = (NN + SCAN_BLK - 1) / SCAN_BLK;   // 98 <= 256

    // workspace carve-out (256B aligned)
    char* ws = (char*)d_ws;
    size_t off = 0;
    auto alloc = [&](size_t bytes) -> void* {
        void* p = ws + off;
        off = (off + bytes + 255) & ~(size_t)255;
        return p;
    };
    int*   flag   = (int*)  alloc(4);
    int*   deg    = (int*)  alloc((size_t)NN * 4);
    float* dinv   = (float*)alloc((size_t)NN * 4);
    int*   e32    = (int*)  alloc((size_t)n2e * 4);        // src32 | dst32
    int*   excl   = (int*)  alloc((size_t)NN * 4);
    int*   bsum   = (int*)  alloc(256 * 4);
    int*   rowptr = (int*)  alloc((size_t)(NN + 1) * 4);
    int*   cursor = (int*)  alloc((size_t)NN * 4);
    int2*  esort  = (int2*) alloc((size_t)E * 8);
    float* bufA   = (float*)alloc((size_t)NN * F * 4);
    float* bufB   = (float*)alloc((size_t)NN * F * 4);
    int* src32 = e32;
    int* dst32 = e32 + E;

    hipMemsetAsync(deg, 0, (size_t)NN * 4, stream);

    detect_kernel<<<1, 64, 0, stream>>>(ei, flag);
    convert_kernel<<<(n2e + 255) / 256, 256, 0, stream>>>(ei, flag, e32, n2e);

    deg_kernel <<<(E + 255) / 256, 256, 0, stream>>>(dst32, deg, E);
    dinv_kernel<<<(NN + 255) / 256, 256, 0, stream>>>(deg, dinv, NN);

    scan1_kernel<<<NB, 256, 0, stream>>>(deg, excl, bsum, NN);
    scan2_kernel<<<1, 256, 0, stream>>>(bsum, NB);
    scan3_kernel<<<(NN + 255) / 256, 256, 0, stream>>>(excl, bsum, rowptr, cursor, NN, E);

    scatter_kernel<<<(E + 255) / 256, 256, 0, stream>>>(src32, dst32, dinv, cursor, esort, E);

    const int lin_blocks = (NN + 63) / 64;   // 1563

    // conv1: x -> bufA (raw conv sums)
    conv_csr_kernel<<<(NN + 3) / 4, 256, 0, stream>>>(x, rowptr, esort, bufA, NN);

    // lin1: relu(bufA) @ W1 + b1, relu -> bufB
    lin1_kernel<<<lin_blocks, 256, 0, stream>>>(bufA, W1, b1, bufB, NN);

    // conv2: bufB -> bufA (raw conv sums)
    conv_csr_kernel<<<(NN + 3) / 4, 256, 0, stream>>>(bufB, rowptr, esort, bufA, NN);

    // lin2 + log_softmax: relu(bufA) @ W2 + b2 -> out
    lin2_kernel<<<lin_blocks, 256, 0, stream>>>(bufA, W2, b2, out, NN);
}